// Round 6
// baseline (382.098 us; speedup 1.0000x reference)
//
#include <hip/hip_runtime.h>
#include <math.h>

namespace {

constexpr int B = 16, H = 512, W = 512;
constexpr int HWc = H * W;                 // 262144
constexpr size_t Nc = (size_t)B * HWc;     // 4194304

// fused tiling: wave owns 42 central cols (lanes 11..52) x 16 central rows.
// 13 strips x 32 bands x 16 images = 6656 waves.
constexpr int NSTRIP = 13, NBAND = 32;
constexpr int NW = NSTRIP * NBAND * B;     // 6656
constexpr int WPI = NSTRIP * NBAND;        // 416 waves per image

// ---------------- DPP lane shifts ----------------
// wave_shr:1 (0x138): lane i <- lane i-1 (lane 0 keeps old=self)
// wave_shl:1 (0x130): lane i <- lane i+1 (lane 63 keeps old=self)
// Self-clamp at wave edges == replicate padding; max/min are symmetric so
// shift-direction interpretation cannot change the result. Edge-lane
// corruption propagates exactly 1 lane per application; total applications
// per pixel: 1 (boundary) + 10 (dilations) = 11 = horizontal halo.
template <int CTRL>
__device__ __forceinline__ float dpp_shift1(float v) {
  int i = __float_as_int(v);
  int r = __builtin_amdgcn_update_dpp(i, i, CTRL, 0xF, 0xF, false);
  return __int_as_float(r);
}
__device__ __forceinline__ float hmax3(float v) {
  return fmaxf(fmaxf(dpp_shift1<0x138>(v), v), dpp_shift1<0x130>(v));
}
__device__ __forceinline__ float hmin3(float v) {
  return fminf(fminf(dpp_shift1<0x138>(v), v), dpp_shift1<0x130>(v));
}

__device__ __forceinline__ float wave_sum(float v) {
#pragma unroll
  for (int off = 32; off > 0; off >>= 1) v += __shfl_down(v, off);
  return v;
}

// --- block-wide sum over 256 threads (finalize only)
__device__ __forceinline__ float block_reduce_256(float v, float* sm, int tid) {
  v = wave_sum(v);
  int lane = tid & 63, wid = tid >> 6;
  if (lane == 0) sm[wid] = v;
  __syncthreads();
  float r = 0.f;
  if (tid == 0) r = sm[0] + sm[1] + sm[2] + sm[3];
  __syncthreads();
  return r;
}

// ---------------- the fused kernel ----------------
// Per wave: load logits/target rows y0-11 .. y0+26 (38 rows, clamped) for its
// 64-lane column window; compute sigmoid + BCE/dice partials on central
// pixels; compute both soft boundaries in-place (vertical rolling max3/min3 +
// DPP horizontal); run both 10-step dilation chains in registers,
// accumulating sum_d (d/10)*(|pred_d - gt_b| + |gt_d - pred_b|) over central
// pixels. No LDS, no intermediate global traffic.
__global__ void __launch_bounds__(64, 4) fused_kernel(
    const float* __restrict__ logits, const int* __restrict__ target,
    float* __restrict__ bce_p, float* __restrict__ sp_p,
    float* __restrict__ st_p, float* __restrict__ spt_p,
    float* __restrict__ hd_p) {
  int lane = threadIdx.x;
  int strip = blockIdx.x;   // 0..12
  int band = blockIdx.y;    // 0..31
  int img = blockIdx.z;     // 0..15
  const float* L = logits + (size_t)img * HWc;
  const int* T = target + (size_t)img * HWc;
  int col = strip * 42 - 11 + lane;
  int colc = min(max(col, 0), W - 1);
  int y0 = band * 16;
  bool central = (lane >= 11 && lane <= 52 && col < W);

  // phase 1: load probs + targets (38 rows), accumulate BCE/dice partials on
  // central rows (mask applied once at the end).
  float ap[38], at[38];
  float s_bce = 0.f, s_p = 0.f, s_t = 0.f, s_pt = 0.f;
#pragma unroll
  for (int r = 0; r < 38; ++r) {
    int gy = min(max(y0 - 11 + r, 0), H - 1);
    float x = L[gy * W + colc];
    float t = (float)T[gy * W + colc];
    float p = 1.f / (1.f + expf(-x));
    if (r >= 11 && r <= 26) {
      s_bce += fmaxf(x, 0.f) - x * t + log1pf(expf(-fabsf(x)));
      s_p += p;
      s_t += t;
      s_pt += p * t;
    }
    ap[r] = p;
    at[r] = t;
  }

  // phase 2: soft boundary in place, rows 1..36 valid afterwards.
  // b[r] = hmax3(vmax3(r)) - hmin3(vmin3(r)); rolling originals in prev/cur.
  {
    float prev = ap[0], cur = ap[1];
#pragma unroll
    for (int r = 1; r <= 36; ++r) {
      float nxt = ap[r + 1];
      float vmx = fmaxf(fmaxf(prev, cur), nxt);
      float vmn = fminf(fminf(prev, cur), nxt);
      prev = cur;
      cur = nxt;
      ap[r] = hmax3(vmx) - hmin3(vmn);
    }
  }
  {
    float prev = at[0], cur = at[1];
#pragma unroll
    for (int r = 1; r <= 36; ++r) {
      float nxt = at[r + 1];
      float vmx = fmaxf(fmaxf(prev, cur), nxt);
      float vmn = fminf(fminf(prev, cur), nxt);
      prev = cur;
      cur = nxt;
      at[r] = hmax3(vmx) - hmin3(vmn);
    }
  }

  // snapshot undilated pred boundary central rows (gt boundary stays intact
  // through chain A, so it needs no snapshot).
  float o_p[16];
#pragma unroll
  for (int k = 0; k < 16; ++k) o_p[k] = ap[11 + k];

  float acc = 0.f;
  // chain A: dilate pred boundary; diff vs (intact) gt boundary central rows.
  // before step d valid rows [d, 37-d]; after: [d+1, 36-d]. central [11,26]
  // stays valid through d=10.
#pragma unroll
  for (int d = 1; d <= 10; ++d) {
    float hp = hmax3(ap[d]);
    float hc = hmax3(ap[d + 1]);
#pragma unroll
    for (int r = d + 1; r <= 36 - d; ++r) {
      float hn = hmax3(ap[r + 1]);
      float nv = fmaxf(fmaxf(hp, hc), hn);
      hp = hc;
      hc = hn;
      ap[r] = nv;
    }
    const float wd = 0.1f * (float)d;
#pragma unroll
    for (int k = 0; k < 16; ++k) acc += wd * fabsf(ap[11 + k] - at[11 + k]);
  }
  // chain B: dilate gt boundary; diff vs snapshot o_p.
#pragma unroll
  for (int d = 1; d <= 10; ++d) {
    float hp = hmax3(at[d]);
    float hc = hmax3(at[d + 1]);
#pragma unroll
    for (int r = d + 1; r <= 36 - d; ++r) {
      float hn = hmax3(at[r + 1]);
      float nv = fmaxf(fmaxf(hp, hc), hn);
      hp = hc;
      hc = hn;
      at[r] = nv;
    }
    const float wd = 0.1f * (float)d;
#pragma unroll
    for (int k = 0; k < 16; ++k) acc += wd * fabsf(at[11 + k] - o_p[k]);
  }

  if (!central) {
    acc = 0.f;
    s_bce = 0.f;
    s_p = 0.f;
    s_t = 0.f;
    s_pt = 0.f;
  }
  s_bce = wave_sum(s_bce);
  s_p = wave_sum(s_p);
  s_t = wave_sum(s_t);
  s_pt = wave_sum(s_pt);
  acc = wave_sum(acc);
  if (lane == 0) {
    int widx = (img * NBAND + band) * NSTRIP + strip;
    bce_p[widx] = s_bce;
    sp_p[widx] = s_p;
    st_p[widx] = s_t;
    spt_p[widx] = s_pt;
    hd_p[widx] = acc;
  }
}

// ---------------- finalize ----------------
__global__ void finalize_kernel(const float* __restrict__ bce_p,
                                const float* __restrict__ sp_p,
                                const float* __restrict__ st_p,
                                const float* __restrict__ spt_p,
                                const float* __restrict__ hd_p,
                                float* __restrict__ out) {
  __shared__ float smr[4];
  __shared__ float simg[16][16][3];
  __shared__ double img_terms[16][2];
  int tid = threadIdx.x;

  float s = 0.f;
  for (int i = tid; i < NW; i += 256) s += bce_p[i];
  float bce_sum = block_reduce_256(s, smr, tid);

  s = 0.f;
  for (int i = tid; i < NW; i += 256) s += hd_p[i];
  float hd_sum = block_reduce_256(s, smr, tid);

  // per-image sums: 16 threads per image, strided over its 416 partials
  int im = tid >> 4, j = tid & 15;
  float sp = 0.f, st = 0.f, spt = 0.f;
  for (int k = j; k < WPI; k += 16) {
    int idx = im * WPI + k;
    sp += sp_p[idx];
    st += st_p[idx];
    spt += spt_p[idx];
  }
  simg[im][j][0] = sp;
  simg[im][j][1] = st;
  simg[im][j][2] = spt;
  __syncthreads();
  if (tid < 16) {
    double dsp = 0.0, dst = 0.0, dspt = 0.0;
    for (int j2 = 0; j2 < 16; ++j2) {
      dsp += (double)simg[tid][j2][0];
      dst += (double)simg[tid][j2][1];
      dspt += (double)simg[tid][j2][2];
    }
    double dice = (2.0 * dspt + 1e-6) / (dsp + dst + 1e-6 + 1e-7);
    double tv = (dspt + 1e-6) /
                (dspt + 0.7 * (dsp - dspt) + 0.3 * (dst - dspt) + 1e-6 + 1e-7);
    img_terms[tid][0] = 1.0 - dice;
    img_terms[tid][1] = pow(1.0 - tv, 0.75);
  }
  __syncthreads();
  if (tid == 0) {
    const double Nd = (double)Nc;
    double dice_l = 0.0, ft_l = 0.0;
    for (int i = 0; i < 16; ++i) {
      dice_l += img_terms[i][0];
      ft_l += img_terms[i][1];
    }
    dice_l /= 16.0;
    ft_l /= 16.0;
    double bce = (double)bce_sum / Nd;
    double hd = ((double)hd_sum / Nd) / (5.5 + 1e-8);
    out[0] = (float)(bce + dice_l + ft_l + 0.1 * hd);
  }
}

}  // namespace

extern "C" void kernel_launch(void* const* d_in, const int* in_sizes, int n_in,
                              void* d_out, int out_size, void* d_ws,
                              size_t ws_size, hipStream_t stream) {
  const float* logits = (const float*)d_in[0];
  const int* target = (const int*)d_in[1];
  float* out = (float*)d_out;

  float* part = (float*)d_ws;
  float* bce_p = part;             // NW
  float* sp_p = part + NW;         // NW
  float* st_p = part + 2 * NW;     // NW
  float* spt_p = part + 3 * NW;    // NW
  float* hd_p = part + 4 * NW;     // NW

  fused_kernel<<<dim3(NSTRIP, NBAND, B), dim3(64), 0, stream>>>(
      logits, target, bce_p, sp_p, st_p, spt_p, hd_p);
  finalize_kernel<<<1, 256, 0, stream>>>(bce_p, sp_p, st_p, spt_p, hd_p, out);
}

// Round 7
// 207.128 us; speedup vs baseline: 1.8447x; 1.8447x over previous
//
#include <hip/hip_runtime.h>
#include <math.h>

namespace {

constexpr int B = 16, H = 512, W = 512;
constexpr int HWc = H * W;                 // 262144
constexpr size_t Nc = (size_t)B * HWc;     // 4194304

// tiling: wave owns 42 central cols (lanes 11..52) x 16 central rows.
// 13 strips x 32 bands x 16 images = 6656 waves per kernel.
constexpr int NSTRIP = 13, NBAND = 32;
constexpr int NW = NSTRIP * NBAND * B;     // 6656
constexpr int WPI = NSTRIP * NBAND;        // 416 waves per image

// ---------------- DPP lane shifts ----------------
// wave_shr:1 (0x138) / wave_shl:1 (0x130), old=self => wave-edge lanes clamp
// to self (replicate). max/min symmetric so direction cannot matter. Edge
// corruption moves 1 lane per application; 1 (boundary) + 10 (chain) = 11 =
// horizontal halo (central lanes 11..52).
template <int CTRL>
__device__ __forceinline__ float dpp_shift1(float v) {
  int i = __float_as_int(v);
  int r = __builtin_amdgcn_update_dpp(i, i, CTRL, 0xF, 0xF, false);
  return __int_as_float(r);
}
__device__ __forceinline__ float hmax3(float v) {
  return fmaxf(fmaxf(dpp_shift1<0x138>(v), v), dpp_shift1<0x130>(v));
}
__device__ __forceinline__ float hmin3(float v) {
  return fminf(fminf(dpp_shift1<0x138>(v), v), dpp_shift1<0x130>(v));
}

__device__ __forceinline__ float wave_sum(float v) {
#pragma unroll
  for (int off = 32; off > 0; off >>= 1) v += __shfl_down(v, off);
  return v;
}

__device__ __forceinline__ float block_reduce_256(float v, float* sm, int tid) {
  v = wave_sum(v);
  int lane = tid & 63, wid = tid >> 6;
  if (lane == 0) sm[wid] = v;
  __syncthreads();
  float r = 0.f;
  if (tid == 0) r = sm[0] + sm[1] + sm[2] + sm[3];
  __syncthreads();
  return r;
}

// Shared chain body: in-place 10x dilate a[1..36] with CONSTANT bounds
// (rows 0/37 are stale -> garbage reaches rows 10/27 at step 10; central
// 11..26 stays exact). All indices compile-time => arrays stay in VGPRs.
// Accumulates sum_d (d/10)*|a[11+k] - ref[k]| over k=0..15.
__device__ __forceinline__ float run_chain(float a[38], const float ref[16]) {
  float acc = 0.f;
#pragma unroll
  for (int d = 1; d <= 10; ++d) {
    float hp = hmax3(a[0]);
    float hc = hmax3(a[1]);
#pragma unroll
    for (int r = 1; r <= 36; ++r) {
      float hn = hmax3(a[r + 1]);
      float nv = fmaxf(fmaxf(hp, hc), hn);
      hp = hc;
      hc = hn;
      a[r] = nv;
    }
    const float wd = 0.1f * (float)d;
#pragma unroll
    for (int k = 0; k < 16; ++k) acc += wd * fabsf(a[11 + k] - ref[k]);
  }
  return acc;
}

// in-place soft boundary rows 1..36 (constant bounds): b = hmax3(vmax3) -
// hmin3(vmin3) of the original values.
__device__ __forceinline__ void soft_boundary(float a[38]) {
  float prev = a[0], cur = a[1];
#pragma unroll
  for (int r = 1; r <= 36; ++r) {
    float nxt = a[r + 1];
    float vmx = fmaxf(fmaxf(prev, cur), nxt);
    float vmn = fminf(fminf(prev, cur), nxt);
    prev = cur;
    cur = nxt;
    a[r] = hmax3(vmx) - hmin3(vmn);
  }
}

// ---------------- kernel A: pred chain + BCE/dice partials ----------------
__global__ void __launch_bounds__(64, 4) chainA_kernel(
    const float* __restrict__ logits, const int* __restrict__ target,
    float* __restrict__ bce_p, float* __restrict__ sp_p,
    float* __restrict__ st_p, float* __restrict__ spt_p,
    float* __restrict__ hdA_p) {
  int lane = threadIdx.x;
  int strip = blockIdx.x, band = blockIdx.y, img = blockIdx.z;
  const float* L = logits + (size_t)img * HWc;
  const int* T = target + (size_t)img * HWc;
  int col = strip * 42 - 11 + lane;
  int colc = min(max(col, 0), W - 1);
  int y0 = band * 16;
  bool central = (lane >= 11 && lane <= 52 && col < W);

  // gt boundary on central rows only (target rows y0-1 .. y0+16)
  float tt[18];
#pragma unroll
  for (int j = 0; j < 18; ++j) {
    int gy = min(max(y0 - 1 + j, 0), H - 1);
    tt[j] = (float)T[gy * W + colc];
  }
  float btc[16];
#pragma unroll
  for (int k = 0; k < 16; ++k) {
    float vmx = fmaxf(fmaxf(tt[k], tt[k + 1]), tt[k + 2]);
    float vmn = fminf(fminf(tt[k], tt[k + 1]), tt[k + 2]);
    btc[k] = hmax3(vmx) - hmin3(vmn);
  }

  // probs (38 rows) + BCE/dice partials on central rows
  float ap[38];
  float s_bce = 0.f, s_p = 0.f, s_t = 0.f, s_pt = 0.f;
#pragma unroll
  for (int r = 0; r < 38; ++r) {
    int gy = min(max(y0 - 11 + r, 0), H - 1);
    float x = L[gy * W + colc];
    float p = 1.f / (1.f + expf(-x));
    if (r >= 11 && r <= 26) {
      float t = tt[r - 10];
      s_bce += fmaxf(x, 0.f) - x * t + log1pf(expf(-fabsf(x)));
      s_p += p;
      s_t += t;
      s_pt += p * t;
    }
    ap[r] = p;
  }

  soft_boundary(ap);
  float acc = run_chain(ap, btc);

  if (!central) {
    acc = 0.f;
    s_bce = 0.f;
    s_p = 0.f;
    s_t = 0.f;
    s_pt = 0.f;
  }
  s_bce = wave_sum(s_bce);
  s_p = wave_sum(s_p);
  s_t = wave_sum(s_t);
  s_pt = wave_sum(s_pt);
  acc = wave_sum(acc);
  if (lane == 0) {
    int widx = (img * NBAND + band) * NSTRIP + strip;
    bce_p[widx] = s_bce;
    sp_p[widx] = s_p;
    st_p[widx] = s_t;
    spt_p[widx] = s_pt;
    hdA_p[widx] = acc;
  }
}

// ---------------- kernel B: gt chain ----------------
__global__ void __launch_bounds__(64, 4) chainB_kernel(
    const float* __restrict__ logits, const int* __restrict__ target,
    float* __restrict__ hdB_p) {
  int lane = threadIdx.x;
  int strip = blockIdx.x, band = blockIdx.y, img = blockIdx.z;
  const float* L = logits + (size_t)img * HWc;
  const int* T = target + (size_t)img * HWc;
  int col = strip * 42 - 11 + lane;
  int colc = min(max(col, 0), W - 1);
  int y0 = band * 16;
  bool central = (lane >= 11 && lane <= 52 && col < W);

  // pred boundary on central rows only (logit rows y0-1 .. y0+16)
  float pp[18];
#pragma unroll
  for (int j = 0; j < 18; ++j) {
    int gy = min(max(y0 - 1 + j, 0), H - 1);
    float x = L[gy * W + colc];
    pp[j] = 1.f / (1.f + expf(-x));
  }
  float bpc[16];
#pragma unroll
  for (int k = 0; k < 16; ++k) {
    float vmx = fmaxf(fmaxf(pp[k], pp[k + 1]), pp[k + 2]);
    float vmn = fminf(fminf(pp[k], pp[k + 1]), pp[k + 2]);
    bpc[k] = hmax3(vmx) - hmin3(vmn);
  }

  float at[38];
#pragma unroll
  for (int r = 0; r < 38; ++r) {
    int gy = min(max(y0 - 11 + r, 0), H - 1);
    at[r] = (float)T[gy * W + colc];
  }

  soft_boundary(at);
  float acc = run_chain(at, bpc);

  acc = central ? acc : 0.f;
  acc = wave_sum(acc);
  if (lane == 0) {
    int widx = (img * NBAND + band) * NSTRIP + strip;
    hdB_p[widx] = acc;
  }
}

// ---------------- finalize ----------------
__global__ void finalize_kernel(const float* __restrict__ bce_p,
                                const float* __restrict__ sp_p,
                                const float* __restrict__ st_p,
                                const float* __restrict__ spt_p,
                                const float* __restrict__ hdA_p,
                                const float* __restrict__ hdB_p,
                                float* __restrict__ out) {
  __shared__ float smr[4];
  __shared__ float simg[16][16][3];
  __shared__ double img_terms[16][2];
  int tid = threadIdx.x;

  float s = 0.f;
  for (int i = tid; i < NW; i += 256) s += bce_p[i];
  float bce_sum = block_reduce_256(s, smr, tid);

  s = 0.f;
  for (int i = tid; i < NW; i += 256) s += hdA_p[i] + hdB_p[i];
  float hd_sum = block_reduce_256(s, smr, tid);

  int im = tid >> 4, j = tid & 15;
  float sp = 0.f, st = 0.f, spt = 0.f;
  for (int k = j; k < WPI; k += 16) {
    int idx = im * WPI + k;
    sp += sp_p[idx];
    st += st_p[idx];
    spt += spt_p[idx];
  }
  simg[im][j][0] = sp;
  simg[im][j][1] = st;
  simg[im][j][2] = spt;
  __syncthreads();
  if (tid < 16) {
    double dsp = 0.0, dst = 0.0, dspt = 0.0;
    for (int j2 = 0; j2 < 16; ++j2) {
      dsp += (double)simg[tid][j2][0];
      dst += (double)simg[tid][j2][1];
      dspt += (double)simg[tid][j2][2];
    }
    double dice = (2.0 * dspt + 1e-6) / (dsp + dst + 1e-6 + 1e-7);
    double tv = (dspt + 1e-6) /
                (dspt + 0.7 * (dsp - dspt) + 0.3 * (dst - dspt) + 1e-6 + 1e-7);
    img_terms[tid][0] = 1.0 - dice;
    img_terms[tid][1] = pow(1.0 - tv, 0.75);
  }
  __syncthreads();
  if (tid == 0) {
    const double Nd = (double)Nc;
    double dice_l = 0.0, ft_l = 0.0;
    for (int i = 0; i < 16; ++i) {
      dice_l += img_terms[i][0];
      ft_l += img_terms[i][1];
    }
    dice_l /= 16.0;
    ft_l /= 16.0;
    double bce = (double)bce_sum / Nd;
    double hd = ((double)hd_sum / Nd) / (5.5 + 1e-8);
    out[0] = (float)(bce + dice_l + ft_l + 0.1 * hd);
  }
}

}  // namespace

extern "C" void kernel_launch(void* const* d_in, const int* in_sizes, int n_in,
                              void* d_out, int out_size, void* d_ws,
                              size_t ws_size, hipStream_t stream) {
  const float* logits = (const float*)d_in[0];
  const int* target = (const int*)d_in[1];
  float* out = (float*)d_out;

  float* part = (float*)d_ws;
  float* bce_p = part;             // NW
  float* sp_p = part + NW;         // NW
  float* st_p = part + 2 * NW;     // NW
  float* spt_p = part + 3 * NW;    // NW
  float* hdA_p = part + 4 * NW;    // NW
  float* hdB_p = part + 5 * NW;    // NW

  dim3 grid(NSTRIP, NBAND, B), blk(64);
  chainA_kernel<<<grid, blk, 0, stream>>>(logits, target, bce_p, sp_p, st_p,
                                          spt_p, hdA_p);
  chainB_kernel<<<grid, blk, 0, stream>>>(logits, target, hdB_p);
  finalize_kernel<<<1, 256, 0, stream>>>(bce_p, sp_p, st_p, spt_p, hdA_p,
                                         hdB_p, out);
}

// Round 8
// 149.809 us; speedup vs baseline: 2.5506x; 1.3826x over previous
//
#include <hip/hip_runtime.h>
#include <math.h>

namespace {

constexpr int B = 16, H = 512, W = 512;
constexpr int HWc = H * W;                 // 262144
constexpr size_t Nc = (size_t)B * HWc;     // 4194304

typedef _Float16 h2 __attribute__((ext_vector_type(2)));

// ---------------- DPP lane shifts ----------------
// wave_shr:1 (0x138) / wave_shl:1 (0x130), old=self => wave-edge lanes clamp
// to self (replicate padding). max is symmetric so direction cannot matter.
// Packed halves (two rows) shift together across lanes (columns) - correct.
template <int CTRL>
__device__ __forceinline__ int dpp_i(int i) {
  return __builtin_amdgcn_update_dpp(i, i, CTRL, 0xF, 0xF, false);
}
template <int CTRL>
__device__ __forceinline__ float dpp_shift1(float v) {
  return __int_as_float(dpp_i<CTRL>(__float_as_int(v)));
}
__device__ __forceinline__ float hmax3(float v) {
  return fmaxf(fmaxf(dpp_shift1<0x138>(v), v), dpp_shift1<0x130>(v));
}
__device__ __forceinline__ float hmin3(float v) {
  return fminf(fminf(dpp_shift1<0x138>(v), v), dpp_shift1<0x130>(v));
}

// packed fp16 helpers
__device__ __forceinline__ h2 pkmax(h2 a, h2 b) {
  return __builtin_elementwise_max(a, b);
}
__device__ __forceinline__ h2 hmax3p(h2 v) {
  int iv = __builtin_bit_cast(int, v);
  h2 r1 = __builtin_bit_cast(h2, dpp_i<0x138>(iv));
  h2 r2 = __builtin_bit_cast(h2, dpp_i<0x130>(iv));
  return pkmax(pkmax(r1, v), r2);
}
__device__ __forceinline__ h2 habs2(h2 v) {
  int iv = __builtin_bit_cast(int, v) & 0x7FFF7FFF;
  return __builtin_bit_cast(h2, iv);
}
// {lo: lo.hi, hi: hi.lo} -> forms the row pair shifted by one row
__device__ __forceinline__ h2 algn(h2 hi, h2 lo) {
  unsigned r = __builtin_amdgcn_alignbit(__builtin_bit_cast(unsigned, hi),
                                         __builtin_bit_cast(unsigned, lo), 16);
  return __builtin_bit_cast(h2, r);
}

__device__ __forceinline__ float wave_sum(float v) {
#pragma unroll
  for (int off = 32; off > 0; off >>= 1) v += __shfl_down(v, off);
  return v;
}

__device__ __forceinline__ float block_reduce_256(float v, float* sm, int tid) {
  v = wave_sum(v);
  int lane = tid & 63, wid = tid >> 6;
  if (lane == 0) sm[wid] = v;
  __syncthreads();
  float r = 0.f;
  if (tid == 0) r = sm[0] + sm[1] + sm[2] + sm[3];
  __syncthreads();
  return r;
}

// ---------------- prep: BCE/dice partials + both boundary maps (fp16) ------
// tile: central 64x32, halo 1 -> LDS 34x66 (sigmoid of logits, and target)
constexpr int PH = 34, PW = 66;

__global__ void __launch_bounds__(256) prep_kernel(
    const float* __restrict__ logits, const int* __restrict__ target,
    _Float16* __restrict__ pred_b, _Float16* __restrict__ gt_b,
    float* __restrict__ bce_p, float* __restrict__ sp_p,
    float* __restrict__ st_p, float* __restrict__ spt_p) {
  __shared__ float smP[PH][PW];
  __shared__ float smT[PH][PW];
  __shared__ float smr[4];
  int tid = threadIdx.x;
  int x0 = blockIdx.x * 64, y0 = blockIdx.y * 32, img = blockIdx.z;
  const float* L = logits + (size_t)img * HWc;
  const int* T = target + (size_t)img * HWc;

  for (int i = tid; i < PH * PW; i += 256) {
    int r = i / PW, c = i - r * PW;
    int gy = min(max(y0 - 1 + r, 0), H - 1);
    int gx = min(max(x0 - 1 + c, 0), W - 1);
    float x = L[gy * W + gx];
    smP[r][c] = 1.f / (1.f + expf(-x));
    smT[r][c] = (float)T[gy * W + gx];
  }
  __syncthreads();

  int tx = tid & 63, ty = tid >> 6;
  float s_bce = 0.f, s_p = 0.f, s_t = 0.f, s_pt = 0.f;
#pragma unroll
  for (int k = 0; k < 8; ++k) {
    int yy = ty + 4 * k;  // 0..31 within tile
    size_t idx = (size_t)img * HWc + (size_t)(y0 + yy) * W + x0 + tx;
    float xl = logits[idx];
    float t = smT[yy + 1][tx + 1];
    s_bce += fmaxf(xl, 0.f) - xl * t + log1pf(expf(-fabsf(xl)));
    float p = smP[yy + 1][tx + 1];
    s_p += p;
    s_t += t;
    s_pt += p * t;
    float mx = -1e30f, mn = 1e30f, gmx = -1e30f, gmn = 1e30f;
#pragma unroll
    for (int dy = 0; dy < 3; ++dy) {
#pragma unroll
      for (int dx = 0; dx < 3; ++dx) {
        float v = smP[yy + dy][tx + dx];
        mx = fmaxf(mx, v);
        mn = fminf(mn, v);
        float g = smT[yy + dy][tx + dx];
        gmx = fmaxf(gmx, g);
        gmn = fminf(gmn, g);
      }
    }
    pred_b[idx] = (_Float16)(mx - mn);
    gt_b[idx] = (_Float16)(gmx - gmn);
  }

  int blk = (blockIdx.z * gridDim.y + blockIdx.y) * gridDim.x + blockIdx.x;
  float r;
  r = block_reduce_256(s_bce, smr, tid);
  if (tid == 0) bce_p[blk] = r;
  r = block_reduce_256(s_p, smr, tid);
  if (tid == 0) sp_p[blk] = r;
  r = block_reduce_256(s_t, smr, tid);
  if (tid == 0) st_p[blk] = r;
  r = block_reduce_256(s_pt, smr, tid);
  if (tid == 0) spt_p[blk] = r;
}

// ---------------- chain: packed fp16 register-resident dilation -------------
// 4 independent waves per 256-thread block; wave owns (strip, band, img,
// chain). Lane owns one column; register a[k] packs image rows (2k, 2k+1) of
// a 56-row window y0-12 .. y0+43. Vertical max3 via alignbit row-pair shifts
// + v_pk_max_f16; horizontal max3 via DPP lane shifts (both halves together).
// Constant bounds k=1..26 (rows 2..53): stale edge rows creep inward 1
// row/step; correct zone after step d = [d+1, 54-d], so at d=10 rows [11,44]
// cover the central rows [12,43] (= y0..y0+31). Lane halo: 10 DPP
// applications <= 10-lane halo; central lanes 10..52 (43 cols/strip, 12
// strips cover 516 >= 512, mask col < 512).
__global__ void __launch_bounds__(256) chain_kernel(
    const _Float16* __restrict__ pred_b, const _Float16* __restrict__ gt_b,
    float* __restrict__ partial) {
  int tid = threadIdx.x;
  int lane = tid & 63;
  int wv = tid >> 6;
  int strip = blockIdx.x * 4 + wv;  // 0..11
  int band = blockIdx.y;            // 0..15
  int bz = blockIdx.z;              // 0..31
  int img = bz & 15, chain = bz >> 4;
  const _Float16* src = (chain ? gt_b : pred_b) + (size_t)img * HWc;
  const _Float16* oth = (chain ? pred_b : gt_b) + (size_t)img * HWc;
  int col = strip * 43 - 10 + lane;
  int colc = min(max(col, 0), W - 1);
  int y0 = band * 32;

  h2 a[28];
#pragma unroll
  for (int k = 0; k < 28; ++k) {
    int r0 = min(max(y0 - 12 + 2 * k, 0), H - 1);
    int r1 = min(max(y0 - 11 + 2 * k, 0), H - 1);
    h2 v;
    v.x = src[r0 * W + colc];
    v.y = src[r1 * W + colc];
    a[k] = v;
  }
  h2 o[16];
#pragma unroll
  for (int j = 0; j < 16; ++j) {
    h2 v;
    v.x = oth[(y0 + 2 * j) * W + colc];
    v.y = oth[(y0 + 2 * j + 1) * W + colc];
    o[j] = v;
  }

  float acc = 0.f;
#pragma unroll
  for (int d = 1; d <= 10; ++d) {
    h2 oldp = a[0];
#pragma unroll
    for (int k = 1; k <= 26; ++k) {
      h2 oldk = a[k];
      h2 sdn = algn(oldk, oldp);    // rows (2k-1, 2k)
      h2 sup = algn(a[k + 1], oldk);  // rows (2k+1, 2k+2); a[k+1] still old
      h2 vm = pkmax(pkmax(sdn, oldk), sup);
      a[k] = hmax3p(vm);
      oldp = oldk;
    }
    h2 acc2;
    acc2.x = (_Float16)0;
    acc2.y = (_Float16)0;
#pragma unroll
    for (int j = 0; j < 16; ++j) {
      acc2 = acc2 + habs2(a[j + 6] - o[j]);  // central pairs k=6..21
    }
    acc += 0.1f * (float)d * ((float)acc2.x + (float)acc2.y);
  }

  bool valid = (lane >= 10 && lane <= 52 && col < W);
  acc = valid ? acc : 0.f;
  acc = wave_sum(acc);
  if (lane == 0) partial[(bz * 16 + band) * 12 + strip] = acc;
}

// ---------------- finalize ----------------
__global__ void finalize_kernel(const float* __restrict__ bce_p,
                                const float* __restrict__ sp_p,
                                const float* __restrict__ st_p,
                                const float* __restrict__ spt_p,
                                const float* __restrict__ chain_p,
                                float* __restrict__ out) {
  __shared__ float smr[4];
  __shared__ double img_terms[16][2];
  int tid = threadIdx.x;

  float s = 0.f;
  for (int i = tid; i < 2048; i += 256) s += bce_p[i];
  float bce_sum = block_reduce_256(s, smr, tid);

  s = 0.f;
  for (int i = tid; i < 6144; i += 256) s += chain_p[i];
  float hd_sum = block_reduce_256(s, smr, tid);

  if (tid < 16) {
    double sp = 0.0, st = 0.0, spt = 0.0;
    for (int j = 0; j < 128; ++j) {
      sp += (double)sp_p[tid * 128 + j];
      st += (double)st_p[tid * 128 + j];
      spt += (double)spt_p[tid * 128 + j];
    }
    double dice = (2.0 * spt + 1e-6) / (sp + st + 1e-6 + 1e-7);
    double tv = (spt + 1e-6) /
                (spt + 0.7 * (sp - spt) + 0.3 * (st - spt) + 1e-6 + 1e-7);
    img_terms[tid][0] = 1.0 - dice;
    img_terms[tid][1] = pow(1.0 - tv, 0.75);
  }
  __syncthreads();
  if (tid == 0) {
    const double Nd = (double)Nc;
    double dice_l = 0.0, ft_l = 0.0;
    for (int i = 0; i < 16; ++i) {
      dice_l += img_terms[i][0];
      ft_l += img_terms[i][1];
    }
    dice_l /= 16.0;
    ft_l /= 16.0;
    double bce = (double)bce_sum / Nd;
    double hd = ((double)hd_sum / Nd) / (5.5 + 1e-8);
    out[0] = (float)(bce + dice_l + ft_l + 0.1 * hd);
  }
}

}  // namespace

extern "C" void kernel_launch(void* const* d_in, const int* in_sizes, int n_in,
                              void* d_out, int out_size, void* d_ws,
                              size_t ws_size, hipStream_t stream) {
  const float* logits = (const float*)d_in[0];
  const int* target = (const int*)d_in[1];
  float* out = (float*)d_out;

  _Float16* pred_b = (_Float16*)d_ws;          // Nc halves (8.4 MB)
  _Float16* gt_b = pred_b + Nc;                // Nc halves
  float* part = (float*)(gt_b + Nc);           // 16 MiB offset, aligned
  float* bce_p = part;            // 2048
  float* sp_p = part + 2048;      // 2048
  float* st_p = part + 4096;      // 2048
  float* spt_p = part + 6144;     // 2048
  float* chain_p = part + 8192;   // 6144

  prep_kernel<<<dim3(8, 16, B), dim3(256), 0, stream>>>(
      logits, target, pred_b, gt_b, bce_p, sp_p, st_p, spt_p);
  chain_kernel<<<dim3(3, 16, 32), dim3(256), 0, stream>>>(pred_b, gt_b,
                                                          chain_p);
  finalize_kernel<<<1, 256, 0, stream>>>(bce_p, sp_p, st_p, spt_p, chain_p,
                                         out);
}